// Round 8
// baseline (127.844 us; speedup 1.0000x reference)
//
#include <hip/hip_runtime.h>

#define EPSF 1e-8f
#define MARGINF 0.5f
#define BN 512
#define DD 768
#define BT 64
#define SPLITK 8
#define KC (DD / SPLITK)  // 96
#define LPAD 104          // shorts per LDS row: 52 dwords, 52%32=20 -> <=2-way on frag reads

typedef __attribute__((ext_vector_type(8))) short bf16x8;
typedef __attribute__((ext_vector_type(4))) float f32x4;

__device__ __forceinline__ short f2bf(float f) {
    unsigned int u = __float_as_uint(f);
    return (short)((u + 0x7FFFu + ((u >> 16) & 1u)) >> 16);  // RNE
}

__device__ __forceinline__ bf16x8 pack8(const float4& a, const float4& b) {
    bf16x8 r;
    r[0] = f2bf(a.x); r[1] = f2bf(a.y); r[2] = f2bf(a.z); r[3] = f2bf(a.w);
    r[4] = f2bf(b.x); r[5] = f2bf(b.y); r[6] = f2bf(b.z); r[7] = f2bf(b.w);
    return r;
}

struct GramSh {
    short As[BT][LPAD];   // 13.3 KB
    short Bs[BT][LPAD];   // 13.3 KB
};
struct TripSh {
    float drow[BN];
    int lab[BN];
    unsigned long long pmask[8];
};
union SharedU { GramSh g; TripSh t; };

// One kernel, 512 blocks x 256 threads, 2 blocks/CU guaranteed co-resident
// (__launch_bounds__(256,2), grid = 2*256, LDS 26.6KB <= 80KB) -> manual
// global barrier via device-scope counter is deadlock-free.
// Block b: invn[b] -> gram partial tile(b) -> barrier -> triplet anchor b -> finalize.
__global__ __launch_bounds__(256, 2) void fused_kernel(const float* __restrict__ x,
                                                       const int* __restrict__ labels,
                                                       float* __restrict__ invn,
                                                       float* __restrict__ dotp,
                                                       double* __restrict__ acc,
                                                       unsigned int* __restrict__ done,
                                                       unsigned int* __restrict__ done2,
                                                       float* __restrict__ out) {
    __shared__ __align__(16) SharedU sh;
    __shared__ float redf[4];
    __shared__ unsigned int redc[4];
    int b = blockIdx.x;
    int t = threadIdx.x;
    int wv = t >> 6, lane = t & 63;

    // ---------- norm of anchor row b ----------
    {
        float s = 0.f;
        if (t < DD / 4) {
            float4 v = *(const float4*)&x[b * DD + t * 4];
            s = v.x * v.x + v.y * v.y + v.z * v.z + v.w * v.w;
        }
        for (int off = 32; off; off >>= 1) s += __shfl_down(s, off, 64);
        if (lane == 0) redf[wv] = s;
        __syncthreads();
        if (t == 0)
            invn[b] = 1.0f / fmaxf(sqrtf(redf[0] + redf[1] + redf[2] + redf[3]), EPSF);
        // no extra sync needed: redf not reused until after later barriers
    }

    // ---------- gram partial: dotp[bz][i][j] over 96-wide k-chunk (R7 engine, verified) ----------
    int bz = b >> 6, bi = (b >> 3) & 7, bj = b & 7;
    int i0 = bi * BT, j0 = bj * BT, kbase = bz * KC;
    {
        int row = t >> 2, fq = t & 3;
        const float* ap = &x[(i0 + row) * DD + kbase + fq * 8];
        const float* bp = &x[(j0 + row) * DD + kbase + fq * 8];
#pragma unroll
        for (int cc = 0; cc < 3; ++cc) {
            float4 a0 = *(const float4*)(ap + cc * 32);
            float4 a1 = *(const float4*)(ap + cc * 32 + 4);
            float4 b0 = *(const float4*)(bp + cc * 32);
            float4 b1 = *(const float4*)(bp + cc * 32 + 4);
            *(bf16x8*)&sh.g.As[row][fq * 8 + cc * 32] = pack8(a0, a1);
            *(bf16x8*)&sh.g.Bs[row][fq * 8 + cc * 32] = pack8(b0, b1);
        }
    }
    __syncthreads();

    {
        int r16 = lane & 15;
        int kb8 = (lane >> 4) * 8;
        f32x4 accf[4];
#pragma unroll
        for (int c = 0; c < 4; ++c) accf[c] = (f32x4){0.f, 0.f, 0.f, 0.f};
#pragma unroll
        for (int s = 0; s < 3; ++s) {
            bf16x8 af = *(const bf16x8*)&sh.g.As[wv * 16 + r16][kb8 + s * 32];
#pragma unroll
            for (int c = 0; c < 4; ++c) {
                bf16x8 bf_ = *(const bf16x8*)&sh.g.Bs[c * 16 + r16][kb8 + s * 32];
                accf[c] = __builtin_amdgcn_mfma_f32_16x16x32_bf16(af, bf_, accf[c], 0, 0, 0);
            }
        }
        // C/D layout: col = lane&15, row = (lane>>4)*4 + reg  [verified]
        float* o = dotp + (size_t)bz * BN * BN;
        int crow = i0 + wv * 16 + (lane >> 4) * 4;
#pragma unroll
        for (int c = 0; c < 4; ++c) {
            int ccol = j0 + c * 16 + r16;
#pragma unroll
            for (int r = 0; r < 4; ++r)
                o[(crow + r) * BN + ccol] = accf[c][r];
        }
    }
    __syncthreads();             // all block's dotp stores drained (vmcnt) before publish
    if (t == 0) {
        __threadfence();         // release: publish dotp + invn at device scope
        atomicAdd(done, 1u);
    }

    // ---------- manual global barrier (all 512 co-resident) ----------
    if (t == 0) {
        while (__hip_atomic_load(done, __ATOMIC_ACQUIRE, __HIP_MEMORY_SCOPE_AGENT) < (unsigned)BN)
            __builtin_amdgcn_s_sleep(8);
    }
    __syncthreads();
    __threadfence();             // acquire: invalidate stale lines before reading dotp/invn

    // ---------- triplet accumulation, anchor i = b ----------
    {
        sh.t.lab[t] = labels[t];
        sh.t.lab[t + 256] = labels[t + 256];
        float inv_i = invn[b];
        float2 iv = *(const float2*)&invn[2 * t];
        float s0 = 0.f, s1 = 0.f;
#pragma unroll
        for (int z = 0; z < SPLITK; ++z) {
            float2 p = *(const float2*)&dotp[(size_t)z * BN * BN + b * BN + 2 * t];
            s0 += p.x; s1 += p.y;
        }
        sh.t.drow[2 * t]     = 1.0f - s0 * inv_i * iv.x;
        sh.t.drow[2 * t + 1] = 1.0f - s1 * inv_i * iv.y;
        __syncthreads();

        int li = sh.t.lab[b];
        if (t < 64) {
            for (int w = 0; w < 8; ++w) {
                int j = (w << 6) | t;
                unsigned long long m = __ballot(sh.t.lab[j] == li && j != b);
                if (t == 0) sh.t.pmask[w] = m;
            }
        }
        __syncthreads();

        float dik0 = sh.t.drow[t];
        float dik1 = sh.t.drow[t + 256];
        bool k0ok = (sh.t.lab[t] != li);
        bool k1ok = (sh.t.lab[t + 256] != li);
        float sum = 0.f;
        unsigned int cnt = 0;
        for (int w = 0; w < 8; ++w) {
            unsigned long long m = sh.t.pmask[w];
            while (m) {
                int j = (w << 6) + __ffsll(m) - 1;
                m &= m - 1;
                float base = sh.t.drow[j] + MARGINF;
                float v0 = base - dik0;
                float v1 = base - dik1;
                sum += (k0ok && v0 > 0.f) ? v0 : 0.f;
                cnt += (k0ok && v0 > EPSF) ? 1u : 0u;
                sum += (k1ok && v1 > 0.f) ? v1 : 0.f;
                cnt += (k1ok && v1 > EPSF) ? 1u : 0u;
            }
        }
        for (int off = 32; off; off >>= 1) {
            sum += __shfl_down(sum, off, 64);
            cnt += __shfl_down(cnt, off, 64);
        }
        if (lane == 0) { redf[wv] = sum; redc[wv] = cnt; }
        __syncthreads();
        if (t == 0) {
            float stot = redf[0] + redf[1] + redf[2] + redf[3];
            unsigned int ctot = redc[0] + redc[1] + redc[2] + redc[3];
            atomicAdd(&acc[0], (double)stot);
            atomicAdd(&acc[1], (double)ctot);
            __threadfence();
            unsigned int old = atomicAdd(done2, 1u);
            if (old == BN - 1) {
                __threadfence();
                double s = atomicAdd(&acc[0], 0.0);   // RMW read at coherence point
                double c = atomicAdd(&acc[1], 0.0);
                out[0] = (float)(s / (c + 1e-8));
            }
        }
    }
}

extern "C" void kernel_launch(void* const* d_in, const int* in_sizes, int n_in,
                              void* d_out, int out_size, void* d_ws, size_t ws_size,
                              hipStream_t stream) {
    const float* x = (const float*)d_in[0];
    const int* labels = (const int*)d_in[1];
    float* out = (float*)d_out;

    char* ws = (char*)d_ws;
    double* acc = (double*)ws;                      // 16 B
    unsigned int* done = (unsigned int*)(ws + 16);  // 4 B
    unsigned int* done2 = (unsigned int*)(ws + 20); // 4 B
    float* invn = (float*)(ws + 256);               // 2 KB
    float* dotp = (float*)(ws + 4096);              // 8 MB

    hipMemsetAsync(ws, 0, 64, stream);              // zero acc/done/done2 (graph-capturable)
    fused_kernel<<<BN, 256, 0, stream>>>(x, labels, invn, dotp, acc, done, done2, out);
}

// Round 9
// 34.740 us; speedup vs baseline: 3.6800x; 3.6800x over previous
//
#include <hip/hip_runtime.h>

#define EPSF 1e-8f
#define MARGINF 0.5f
#define BN 512
#define DD 768
#define BT 64
#define SPLITK 8
#define KC (DD / SPLITK)  // 96
#define LPAD 104          // shorts per LDS row: 52 dwords, 52%32=20 -> <=2-way on frag reads

typedef __attribute__((ext_vector_type(8))) short bf16x8;
typedef __attribute__((ext_vector_type(4))) float f32x4;

__device__ __forceinline__ short f2bf(float f) {
    unsigned int u = __float_as_uint(f);
    return (short)((u + 0x7FFFu + ((u >> 16) & 1u)) >> 16);  // RNE
}

__device__ __forceinline__ bf16x8 pack8(const float4& a, const float4& b) {
    bf16x8 r;
    r[0] = f2bf(a.x); r[1] = f2bf(a.y); r[2] = f2bf(a.z); r[3] = f2bf(a.w);
    r[4] = f2bf(b.x); r[5] = f2bf(b.y); r[6] = f2bf(b.z); r[7] = f2bf(b.w);
    return r;
}

// ---------------- Node 1: MFMA gram partials (blocks 0..511) + norms (512..519) ----------------
// Identical engine to R7 (48.1 us run) — unchanged for clean A/B on the atomic path.
__global__ __launch_bounds__(256) void prep_kernel(const float* __restrict__ x,
                                                   float* __restrict__ invn,
                                                   float* __restrict__ dotp) {
    int b = blockIdx.x;
    int t = threadIdx.x;

    if (b >= BN) {
        int rbase = (b - BN) * 64;
        int w = t >> 6, lane = t & 63;
        for (int r = w; r < 64; r += 4) {
            int row = rbase + r;
            float s = 0.f;
#pragma unroll
            for (int c = 0; c < 3; ++c) {
                float4 v = *(const float4*)&x[row * DD + (lane + c * 64) * 4];
                s += v.x * v.x + v.y * v.y + v.z * v.z + v.w * v.w;
            }
            for (int off = 32; off; off >>= 1) s += __shfl_down(s, off, 64);
            if (lane == 0) invn[row] = 1.0f / fmaxf(sqrtf(s), EPSF);
        }
        return;
    }

    __shared__ __align__(16) short As[BT][LPAD];   // 13.3 KB
    __shared__ __align__(16) short Bs[BT][LPAD];   // 26.6 KB total
    int bz = b >> 6, bi = (b >> 3) & 7, bj = b & 7;
    int i0 = bi * BT, j0 = bj * BT, kbase = bz * KC;

    {
        int row = t >> 2, fq = t & 3;
        const float* ap = &x[(i0 + row) * DD + kbase + fq * 8];
        const float* bp = &x[(j0 + row) * DD + kbase + fq * 8];
#pragma unroll
        for (int cc = 0; cc < 3; ++cc) {
            float4 a0 = *(const float4*)(ap + cc * 32);
            float4 a1 = *(const float4*)(ap + cc * 32 + 4);
            float4 b0 = *(const float4*)(bp + cc * 32);
            float4 b1 = *(const float4*)(bp + cc * 32 + 4);
            *(bf16x8*)&As[row][fq * 8 + cc * 32] = pack8(a0, a1);
            *(bf16x8*)&Bs[row][fq * 8 + cc * 32] = pack8(b0, b1);
        }
    }
    __syncthreads();

    int wv = t >> 6, lane = t & 63;
    int r16 = lane & 15;
    int kb8 = (lane >> 4) * 8;

    f32x4 accf[4];
#pragma unroll
    for (int c = 0; c < 4; ++c) accf[c] = (f32x4){0.f, 0.f, 0.f, 0.f};

#pragma unroll
    for (int s = 0; s < 3; ++s) {
        bf16x8 af = *(const bf16x8*)&As[wv * 16 + r16][kb8 + s * 32];
#pragma unroll
        for (int c = 0; c < 4; ++c) {
            bf16x8 bf_ = *(const bf16x8*)&Bs[c * 16 + r16][kb8 + s * 32];
            accf[c] = __builtin_amdgcn_mfma_f32_16x16x32_bf16(af, bf_, accf[c], 0, 0, 0);
        }
    }

    // C/D layout: col = lane&15, row = (lane>>4)*4 + reg   [verified R6/R7]
    float* o = dotp + (size_t)bz * BN * BN;
    int crow = i0 + wv * 16 + (lane >> 4) * 4;
#pragma unroll
    for (int c = 0; c < 4; ++c) {
        int ccol = j0 + c * 16 + r16;
#pragma unroll
        for (int r = 0; r < 4; ++r)
            o[(crow + r) * BN + ccol] = accf[c][r];
    }
}

// ---------------- Node 2: triplet accumulation -> PRIVATE per-block partials ----------------
// No atomics anywhere: block i writes psum[i], pcnt[i] with plain stores.
__global__ __launch_bounds__(256) void triplet_kernel(const float* __restrict__ dotp,
                                                      const float* __restrict__ invn,
                                                      const int* __restrict__ labels,
                                                      float* __restrict__ psum,
                                                      unsigned int* __restrict__ pcnt) {
    int i = blockIdx.x;
    int t = threadIdx.x;
    __shared__ float drow[BN];
    __shared__ int lab[BN];
    __shared__ unsigned long long pmask[8];
    __shared__ float redf[4];
    __shared__ unsigned int redc[4];
    lab[t] = labels[t];
    lab[t + 256] = labels[t + 256];
    float inv_i = invn[i];
#pragma unroll
    for (int e0 = 0; e0 < BN; e0 += 256) {
        int e = e0 + t;
        float s = 0.f;
#pragma unroll
        for (int z = 0; z < SPLITK; ++z) s += dotp[(size_t)z * BN * BN + i * BN + e];
        drow[e] = 1.0f - s * inv_i * invn[e];
    }
    __syncthreads();
    int li = lab[i];
    if (t < 64) {
        for (int w = 0; w < 8; ++w) {
            int j = (w << 6) | t;
            unsigned long long m = __ballot(lab[j] == li && j != i);
            if (t == 0) pmask[w] = m;
        }
    }
    __syncthreads();
    float dik0 = drow[t];
    float dik1 = drow[t + 256];
    bool k0ok = (lab[t] != li);
    bool k1ok = (lab[t + 256] != li);
    float sum = 0.f;
    unsigned int cnt = 0;
    for (int w = 0; w < 8; ++w) {
        unsigned long long m = pmask[w];
        while (m) {
            int j = (w << 6) + __ffsll(m) - 1;
            m &= m - 1;
            float base = drow[j] + MARGINF;
            float v0 = base - dik0;
            float v1 = base - dik1;
            if (k0ok) {
                if (v0 > 0.f) sum += v0;
                if (v0 > EPSF) cnt++;
            }
            if (k1ok) {
                if (v1 > 0.f) sum += v1;
                if (v1 > EPSF) cnt++;
            }
        }
    }
    for (int off = 32; off; off >>= 1) {
        sum += __shfl_down(sum, off, 64);
        cnt += __shfl_down(cnt, off, 64);
    }
    if ((t & 63) == 0) { redf[t >> 6] = sum; redc[t >> 6] = cnt; }
    __syncthreads();
    if (t == 0) {
        psum[i] = redf[0] + redf[1] + redf[2] + redf[3];
        pcnt[i] = redc[0] + redc[1] + redc[2] + redc[3];
    }
}

// ---------------- Node 3: final reduce (1 block, no atomics, deterministic) ----------------
__global__ __launch_bounds__(256) void reduce_kernel(const float* __restrict__ psum,
                                                     const unsigned int* __restrict__ pcnt,
                                                     float* __restrict__ out) {
    int t = threadIdx.x;
    double s = (double)psum[t] + (double)psum[t + 256];
    double c = (double)pcnt[t] + (double)pcnt[t + 256];
    for (int off = 32; off; off >>= 1) {
        s += __shfl_down(s, off, 64);
        c += __shfl_down(c, off, 64);
    }
    __shared__ double sred[4], cred[4];
    if ((t & 63) == 0) { sred[t >> 6] = s; cred[t >> 6] = c; }
    __syncthreads();
    if (t == 0) {
        double stot = sred[0] + sred[1] + sred[2] + sred[3];
        double ctot = cred[0] + cred[1] + cred[2] + cred[3];
        out[0] = (float)(stot / (ctot + 1e-8));
    }
}

extern "C" void kernel_launch(void* const* d_in, const int* in_sizes, int n_in,
                              void* d_out, int out_size, void* d_ws, size_t ws_size,
                              hipStream_t stream) {
    const float* x = (const float*)d_in[0];
    const int* labels = (const int*)d_in[1];
    float* out = (float*)d_out;

    char* ws = (char*)d_ws;
    float* invn = (float*)(ws + 256);               // 2 KB
    float* psum = (float*)(ws + 4096);              // 2 KB
    unsigned int* pcnt = (unsigned int*)(ws + 8192);// 2 KB
    float* dotp = (float*)(ws + 16384);             // 8 MB

    prep_kernel<<<BN + 8, 256, 0, stream>>>(x, invn, dotp);
    triplet_kernel<<<BN, 256, 0, stream>>>(dotp, invn, labels, psum, pcnt);
    reduce_kernel<<<1, 256, 0, stream>>>(psum, pcnt, out);
}

// Round 10
// 24.444 us; speedup vs baseline: 5.2301x; 1.4212x over previous
//
#include <hip/hip_runtime.h>

#define EPSF 1e-8f
#define MARGINF 0.5f
#define BN 512
#define DD 768
#define BT 64
#define SPLITK 8
#define KC (DD / SPLITK)  // 96
#define LPAD 104          // shorts per LDS row: 52 dwords, 52%32=20 -> <=2-way on frag reads
#define NORMBLK 128       // norm: 128 blocks x 4 waves x 1 row each (no serial loop)

typedef __attribute__((ext_vector_type(8))) short bf16x8;
typedef __attribute__((ext_vector_type(4))) float f32x4;

__device__ __forceinline__ short f2bf(float f) {
    unsigned int u = __float_as_uint(f);
    return (short)((u + 0x7FFFu + ((u >> 16) & 1u)) >> 16);  // RNE
}

__device__ __forceinline__ bf16x8 pack8(const float4& a, const float4& b) {
    bf16x8 r;
    r[0] = f2bf(a.x); r[1] = f2bf(a.y); r[2] = f2bf(a.z); r[3] = f2bf(a.w);
    r[4] = f2bf(b.x); r[5] = f2bf(b.y); r[6] = f2bf(b.z); r[7] = f2bf(b.w);
    return r;
}

// ---------------- Node 1: MFMA gram partials (blocks 0..511) + norms (512..639) ----------------
__global__ __launch_bounds__(256) void prep_kernel(const float* __restrict__ x,
                                                   float* __restrict__ invn,
                                                   float* __restrict__ dotp) {
    int b = blockIdx.x;
    int t = threadIdx.x;
    int wv = t >> 6, lane = t & 63;

    if (b >= BN) {
        // ----- norm task: one row per wave, no serial loop -----
        int row = (b - BN) * 4 + wv;
        float s = 0.f;
#pragma unroll
        for (int c = 0; c < 3; ++c) {
            float4 v = *(const float4*)&x[row * DD + (lane + c * 64) * 4];
            s += v.x * v.x + v.y * v.y + v.z * v.z + v.w * v.w;
        }
        for (int off = 32; off; off >>= 1) s += __shfl_down(s, off, 64);
        if (lane == 0) invn[row] = 1.0f / fmaxf(sqrtf(s), EPSF);
        return;
    }

    __shared__ __align__(16) short As[BT][LPAD];   // 13.3 KB
    __shared__ __align__(16) short Bs[BT][LPAD];   // 26.6 KB total
    int bz = b >> 6, bi = (b >> 3) & 7, bj = b & 7;
    int i0 = bi * BT, j0 = bj * BT, kbase = bz * KC;

    {
        int row = t >> 2, fq = t & 3;
        const float* ap = &x[(i0 + row) * DD + kbase + fq * 8];
        const float* bp = &x[(j0 + row) * DD + kbase + fq * 8];
#pragma unroll
        for (int cc = 0; cc < 3; ++cc) {
            float4 a0 = *(const float4*)(ap + cc * 32);
            float4 a1 = *(const float4*)(ap + cc * 32 + 4);
            float4 b0 = *(const float4*)(bp + cc * 32);
            float4 b1 = *(const float4*)(bp + cc * 32 + 4);
            *(bf16x8*)&As[row][fq * 8 + cc * 32] = pack8(a0, a1);
            *(bf16x8*)&Bs[row][fq * 8 + cc * 32] = pack8(b0, b1);
        }
    }
    __syncthreads();

    int r16 = lane & 15;
    int kb8 = (lane >> 4) * 8;

    f32x4 accf[4];
#pragma unroll
    for (int c = 0; c < 4; ++c) accf[c] = (f32x4){0.f, 0.f, 0.f, 0.f};

#pragma unroll
    for (int s = 0; s < 3; ++s) {
        bf16x8 af = *(const bf16x8*)&As[wv * 16 + r16][kb8 + s * 32];
#pragma unroll
        for (int c = 0; c < 4; ++c) {
            bf16x8 bf_ = *(const bf16x8*)&Bs[c * 16 + r16][kb8 + s * 32];
            accf[c] = __builtin_amdgcn_mfma_f32_16x16x32_bf16(af, bf_, accf[c], 0, 0, 0);
        }
    }

    // C/D layout: col = lane&15, row = (lane>>4)*4 + reg   [verified R6-R9]
    float* o = dotp + (size_t)bz * BN * BN;
    int crow = i0 + wv * 16 + (lane >> 4) * 4;
#pragma unroll
    for (int c = 0; c < 4; ++c) {
        int ccol = j0 + c * 16 + r16;
#pragma unroll
        for (int r = 0; r < 4; ++r)
            o[(crow + r) * BN + ccol] = accf[c][r];
    }
}

// ---------------- Node 2: triplet accumulation, compact positive list ----------------
// Block i: drow via split-K sum; positives compacted in ascending-j order (same
// per-thread summation order as the bit-walk -> bitwise-identical result);
// main loop = unrolled independent broadcast LDS reads (no loop-carried load dep).
__global__ __launch_bounds__(256) void triplet_kernel(const float* __restrict__ dotp,
                                                      const float* __restrict__ invn,
                                                      const int* __restrict__ labels,
                                                      float* __restrict__ psum,
                                                      unsigned int* __restrict__ pcnt) {
    int i = blockIdx.x;
    int t = threadIdx.x;
    int w = t >> 6, lane = t & 63;
    __shared__ float drow[BN];
    __shared__ int lab[BN];
    __shared__ float dpos[520];
    __shared__ int wcnt[8];
    __shared__ int woff[9];
    __shared__ float redf[4];
    __shared__ unsigned int redc[4];

    lab[t] = labels[t];
    lab[t + 256] = labels[t + 256];
    float inv_i = invn[i];
#pragma unroll
    for (int e0 = 0; e0 < BN; e0 += 256) {
        int e = e0 + t;
        float s = 0.f;
#pragma unroll
        for (int z = 0; z < SPLITK; ++z) s += dotp[(size_t)z * BN * BN + i * BN + e];
        drow[e] = 1.0f - s * inv_i * invn[e];
    }
    __syncthreads();

    int li = lab[i];
    bool p0 = (lab[t] == li) && (t != i);
    bool p1 = (lab[t + 256] == li) && ((t + 256) != i);
    unsigned long long m0 = __ballot(p0);
    unsigned long long m1 = __ballot(p1);
    if (lane == 0) { wcnt[w] = __popcll(m0); wcnt[4 + w] = __popcll(m1); }
    __syncthreads();
    if (t == 0) {
        int s = 0;
#pragma unroll
        for (int q = 0; q < 8; ++q) { woff[q] = s; s += wcnt[q]; }
        woff[8] = s;
    }
    __syncthreads();
    unsigned long long lmask = (1ull << lane) - 1ull;
    if (p0) dpos[woff[w] + __popcll(m0 & lmask)] = drow[t] + MARGINF;
    if (p1) dpos[woff[4 + w] + __popcll(m1 & lmask)] = drow[t + 256] + MARGINF;
    int npos = woff[8];
    int npad = (npos + 7) & ~7;
    if (t < npad - npos) dpos[npos + t] = -1e30f;   // pad: contributes nothing
    __syncthreads();

    float dik0 = drow[t];
    float dik1 = drow[t + 256];
    bool k0ok = (lab[t] != li);
    bool k1ok = (lab[t + 256] != li);
    float sum = 0.f;
    unsigned int cnt = 0;
    for (int n = 0; n < npad; n += 8) {
#pragma unroll
        for (int u = 0; u < 8; ++u) {
            float base = dpos[n + u];          // wave-uniform broadcast, independent
            float v0 = base - dik0;
            float v1 = base - dik1;
            if (k0ok) {
                sum += fmaxf(v0, 0.f);
                if (v0 > EPSF) cnt++;
            }
            if (k1ok) {
                sum += fmaxf(v1, 0.f);
                if (v1 > EPSF) cnt++;
            }
        }
    }
    for (int off = 32; off; off >>= 1) {
        sum += __shfl_down(sum, off, 64);
        cnt += __shfl_down(cnt, off, 64);
    }
    if (lane == 0) { redf[w] = sum; redc[w] = cnt; }
    __syncthreads();
    if (t == 0) {
        psum[i] = redf[0] + redf[1] + redf[2] + redf[3];
        pcnt[i] = redc[0] + redc[1] + redc[2] + redc[3];
    }
}

// ---------------- Node 3: final reduce (1 block, deterministic) ----------------
__global__ __launch_bounds__(256) void reduce_kernel(const float* __restrict__ psum,
                                                     const unsigned int* __restrict__ pcnt,
                                                     float* __restrict__ out) {
    int t = threadIdx.x;
    double s = (double)psum[t] + (double)psum[t + 256];
    double c = (double)pcnt[t] + (double)pcnt[t + 256];
    for (int off = 32; off; off >>= 1) {
        s += __shfl_down(s, off, 64);
        c += __shfl_down(c, off, 64);
    }
    __shared__ double sred[4], cred[4];
    if ((t & 63) == 0) { sred[t >> 6] = s; cred[t >> 6] = c; }
    __syncthreads();
    if (t == 0) {
        double stot = sred[0] + sred[1] + sred[2] + sred[3];
        double ctot = cred[0] + cred[1] + cred[2] + cred[3];
        out[0] = (float)(stot / (ctot + 1e-8));
    }
}

extern "C" void kernel_launch(void* const* d_in, const int* in_sizes, int n_in,
                              void* d_out, int out_size, void* d_ws, size_t ws_size,
                              hipStream_t stream) {
    const float* x = (const float*)d_in[0];
    const int* labels = (const int*)d_in[1];
    float* out = (float*)d_out;

    char* ws = (char*)d_ws;
    float* invn = (float*)(ws + 256);               // 2 KB
    float* psum = (float*)(ws + 4096);              // 2 KB
    unsigned int* pcnt = (unsigned int*)(ws + 8192);// 2 KB
    float* dotp = (float*)(ws + 16384);             // 8 MB

    prep_kernel<<<BN + NORMBLK, 256, 0, stream>>>(x, invn, dotp);
    triplet_kernel<<<BN, 256, 0, stream>>>(dotp, invn, labels, psum, pcnt);
    reduce_kernel<<<1, 256, 0, stream>>>(psum, pcnt, out);
}